// Round 1
// baseline (237.372 us; speedup 1.0000x reference)
//
#include <hip/hip_runtime.h>
#include <hip/hip_bf16.h>
#include <stdint.h>

typedef __bf16 bf16;
typedef __attribute__((ext_vector_type(8))) __bf16 bf16x8;
typedef __attribute__((ext_vector_type(4))) __bf16 bf16x4;
typedef __attribute__((ext_vector_type(4))) float f32x4;

// ---------------- workspace layout (bytes) ----------------
// xb  [32768,512] bf16  @0          (reused as kT [4,512,8192] after qkv gemm)
// Wb  [1536,512]  bf16  @33554432
// qb  [32768,512] bf16  @35127296
// kb  [32768,512] bf16  @68681728   (reused as vT [4,512,8192] after transpose)
// vb  [32768,512] bf16  @102236160  (reused as P [8,4,512,512] f32, then attn bf16)
// KVb [4,512,512] bf16  @135790592
#define OFF_XB   0L
#define OFF_WB   33554432L
#define OFF_QB   35127296L
#define OFF_KB   68681728L
#define OFF_VB   102236160L
#define OFF_KVB  135790592L
#define WS_NEED  137887744L

// ---------------- async global->LDS (16B per lane) ----------------
typedef const __attribute__((address_space(1))) void* gas_p;
typedef __attribute__((address_space(3))) void* las_p;

__device__ __forceinline__ void gload16(const void* g, void* l) {
  __builtin_amdgcn_global_load_lds((gas_p)(uintptr_t)g,
                                   (las_p)(uint32_t)(uintptr_t)l, 16, 0, 0);
}

// ---------------- shared 128x128 B^T-form GEMM core ----------------
// C[128,128] += A[128, kbeg:kend] * B[128, kbeg:kend]^T
// A row-major [*, lda], B row-major [*, ldb]; K contiguous in both.
// 256 threads = 4 waves (2x2), each wave 64x64 via 4x4 16x16x32 fragments.
__device__ __forceinline__ void gemm_core(
    const bf16* __restrict__ Ab, const bf16* __restrict__ Bb,
    long lda, long ldb, int kbeg, int kend,
    bf16* As, bf16* Bs, f32x4 (&acc)[4][4])
{
  const int tid  = threadIdx.x;
  const int wid  = tid >> 6;
  const int lane = tid & 63;
  const int wr   = wid >> 1, wc = wid & 1;

  // staging map: chunk c = (i*4 + wid)*64 + lane covers row c>>2, cols (c&3)*8..+8
  const int rr = wid * 16 + (lane >> 2);
  const int cc = (lane & 3) * 8;
  const bf16* gA0 = Ab + (long)rr * lda + cc;
  const bf16* gA1 = gA0 + 64 * lda;
  const bf16* gB0 = Bb + (long)rr * ldb + cc;
  const bf16* gB1 = gB0 + 64 * ldb;
  bf16* lA0 = As + wid * 512;        // wave-uniform LDS bases
  bf16* lA1 = As + (4 + wid) * 512;
  bf16* lB0 = Bs + wid * 512;
  bf16* lB1 = Bs + (4 + wid) * 512;

  const int aoff = (lane & 15) * 32 + (lane >> 4) * 8;

  for (int k0 = kbeg; k0 < kend; k0 += 32) {
    gload16(gA0 + k0, lA0);
    gload16(gA1 + k0, lA1);
    gload16(gB0 + k0, lB0);
    gload16(gB1 + k0, lB1);
    __syncthreads();   // drains vmcnt -> LDS tiles valid

    bf16x8 af[4], bfr[4];
#pragma unroll
    for (int m = 0; m < 4; ++m)
      af[m] = *(const bf16x8*)(As + (wr * 64 + m * 16) * 32 + aoff);
#pragma unroll
    for (int n = 0; n < 4; ++n)
      bfr[n] = *(const bf16x8*)(Bs + (wc * 64 + n * 16) * 32 + aoff);
#pragma unroll
    for (int m = 0; m < 4; ++m)
#pragma unroll
      for (int n = 0; n < 4; ++n)
        acc[m][n] = __builtin_amdgcn_mfma_f32_16x16x32_bf16(af[m], bfr[n], acc[m][n], 0, 0, 0);
    __syncthreads();   // protect LDS before next stage
  }
}

// ---------------- casts ----------------
__global__ void cast_x_kernel(const float* __restrict__ in, bf16* __restrict__ out, int n8) {
  int i = blockIdx.x * blockDim.x + threadIdx.x;
  int stride = gridDim.x * blockDim.x;
  for (; i < n8; i += stride) {
    const float* p = in + (long)i * 8;
    float4 a = *(const float4*)p;
    float4 b = *(const float4*)(p + 4);
    bf16x8 o;
    o[0] = (bf16)a.x; o[1] = (bf16)a.y; o[2] = (bf16)a.z; o[3] = (bf16)a.w;
    o[4] = (bf16)b.x; o[5] = (bf16)b.y; o[6] = (bf16)b.z; o[7] = (bf16)b.w;
    *(bf16x8*)(out + (long)i * 8) = o;
  }
}

__global__ void cast_w_kernel(const float* __restrict__ Wq, const float* __restrict__ Wk,
                              const float* __restrict__ Wv, bf16* __restrict__ Wb) {
  int i = blockIdx.x * 256 + threadIdx.x;            // 98304 chunks of 8
  const float* src = (i < 32768) ? Wq : (i < 65536) ? Wk : Wv;
  long j = (long)(i & 32767) * 8;
  float4 a = *(const float4*)(src + j);
  float4 b = *(const float4*)(src + j + 4);
  bf16x8 o;
  o[0] = (bf16)a.x; o[1] = (bf16)a.y; o[2] = (bf16)a.z; o[3] = (bf16)a.w;
  o[4] = (bf16)b.x; o[5] = (bf16)b.y; o[6] = (bf16)b.z; o[7] = (bf16)b.w;
  *(bf16x8*)(Wb + (long)i * 8) = o;
}

// ---------------- fused QKV projection GEMM ----------------
// A = xb [32768,512]; B = Wb [1536,512] (q|k|v concat); C tiles -> qb/kb/vb with
// bias add and elu1 (q,k only).
__global__ __launch_bounds__(256) void gemm_qkv(
    const bf16* __restrict__ A, const bf16* __restrict__ Bw,
    const float* __restrict__ bq, const float* __restrict__ bk, const float* __restrict__ bv,
    bf16* __restrict__ qout, bf16* __restrict__ kout, bf16* __restrict__ vout)
{
  __shared__ bf16 As[4096];
  __shared__ bf16 Bs[4096];
  const int bm = blockIdx.x, tn = blockIdx.y;
  const bf16* Ab = A + (long)bm * 128 * 512;
  const bf16* Bb = Bw + (long)tn * 128 * 512;

  f32x4 acc[4][4] = {};
  gemm_core(Ab, Bb, 512, 512, 0, 512, As, Bs, acc);

  const int lane = threadIdx.x & 63, wid = threadIdx.x >> 6;
  const int wr = wid >> 1, wc = wid & 1;
  const int seg = tn >> 2;                           // 0=q 1=k 2=v
  const float* bias = (seg == 0) ? bq : (seg == 1) ? bk : bv;
  bf16* outp = (seg == 0) ? qout : (seg == 1) ? kout : vout;
  const int colbase = (tn & 3) * 128 + wc * 64;
  const int rowbase = bm * 128 + wr * 64;

#pragma unroll
  for (int n = 0; n < 4; ++n) {
    int col = colbase + n * 16 + (lane & 15);
    float bia = bias[col];
#pragma unroll
    for (int m = 0; m < 4; ++m) {
      int r0 = rowbase + m * 16 + (lane >> 4) * 4;
#pragma unroll
      for (int j = 0; j < 4; ++j) {
        float v = acc[m][n][j] + bia;
        if (seg < 2) v = (v > 0.f) ? (v + 1.f) : expf(v);   // elu1
        outp[(long)(r0 + j) * 512 + col] = (bf16)v;
      }
    }
  }
}

// ---------------- 64x64 tile transpose [B*8192,512] -> [B,512,8192] ----------------
__global__ __launch_bounds__(256) void transpose64(const bf16* __restrict__ in, bf16* __restrict__ out) {
  __shared__ ushort t2[64][72];   // row stride 144B (16B aligned)
  const int s0 = blockIdx.x * 64, d0 = blockIdx.y * 64, b = blockIdx.z;
  const ushort* inp = (const ushort*)in + (long)b * 8192 * 512;
  ushort* outp = (ushort*)out + (long)b * 512 * 8192;
  const int r = threadIdx.x >> 3, ch = threadIdx.x & 7;
#pragma unroll
  for (int i = 0; i < 2; ++i) {
    int rr = r + i * 32;
    uint4 v = *(const uint4*)&inp[(long)(s0 + rr) * 512 + d0 + ch * 8];
    const ushort* pv = (const ushort*)&v;
#pragma unroll
    for (int j = 0; j < 8; ++j) t2[ch * 8 + j][rr] = pv[j];
  }
  __syncthreads();
#pragma unroll
  for (int i = 0; i < 2; ++i) {
    int dd = r + i * 32;
    uint4 v = *(const uint4*)&t2[dd][ch * 8];
    *(uint4*)&outp[(long)(d0 + dd) * 8192 + s0 + ch * 8] = v;
  }
}

// ---------------- KV^T GEMM, split-K=8 (deterministic partials) ----------------
// C[e,d] = sum_s v[s,e]*k[s,d] ; A = vT rows e, B = kT rows d, K = s.
__global__ __launch_bounds__(256) void gemm_kv(
    const bf16* __restrict__ vT, const bf16* __restrict__ kT, float* __restrict__ P)
{
  __shared__ bf16 As[4096];
  __shared__ bf16 Bs[4096];
  const int te = blockIdx.x >> 2, td = blockIdx.x & 3;
  const int sk = blockIdx.y, b = blockIdx.z;
  const bf16* Ab = vT + (long)b * 512 * 8192 + (long)te * 128 * 8192;
  const bf16* Bb = kT + (long)b * 512 * 8192 + (long)td * 128 * 8192;

  f32x4 acc[4][4] = {};
  gemm_core(Ab, Bb, 8192, 8192, sk * 1024, sk * 1024 + 1024, As, Bs, acc);

  const int lane = threadIdx.x & 63, wid = threadIdx.x >> 6;
  const int wr = wid >> 1, wc = wid & 1;
  float* Cb = P + ((long)sk * 4 + b) * 262144;
#pragma unroll
  for (int n = 0; n < 4; ++n) {
    int d = td * 128 + wc * 64 + n * 16 + (lane & 15);
#pragma unroll
    for (int m = 0; m < 4; ++m) {
      int e0 = te * 128 + wr * 64 + m * 16 + (lane >> 4) * 4;
#pragma unroll
      for (int j = 0; j < 4; ++j)
        Cb[(long)(e0 + j) * 512 + d] = acc[m][n][j];
    }
  }
}

__global__ void reduce_kv(const float* __restrict__ P, bf16* __restrict__ KVb) {
  long o = ((long)blockIdx.x * 256 + threadIdx.x) * 4;   // over 4*512*512 elems
  int b = (int)(o >> 18);
  long rem = o & 262143L;
  float4 s = make_float4(0.f, 0.f, 0.f, 0.f);
  for (int sk = 0; sk < 8; ++sk) {
    float4 p = *(const float4*)(P + ((long)sk * 4 + b) * 262144 + rem);
    s.x += p.x; s.y += p.y; s.z += p.z; s.w += p.w;
  }
  bf16x4 ov;
  ov[0] = (bf16)s.x; ov[1] = (bf16)s.y; ov[2] = (bf16)s.z; ov[3] = (bf16)s.w;
  *(bf16x4*)(KVb + o) = ov;
}

// ---------------- attn GEMM: C[s,e] = sum_d q[s,d]*KVT[e,d] ----------------
__global__ __launch_bounds__(256) void gemm_attn(
    const bf16* __restrict__ Q, const bf16* __restrict__ KVb, bf16* __restrict__ attn)
{
  __shared__ bf16 As[4096];
  __shared__ bf16 Bs[4096];
  const int bm = blockIdx.x, tn = blockIdx.y;
  const int b = bm >> 6;                       // 64 m-tiles per batch
  const bf16* Ab = Q + (long)bm * 128 * 512;
  const bf16* Bb = KVb + (long)b * 262144 + (long)tn * 128 * 512;

  f32x4 acc[4][4] = {};
  gemm_core(Ab, Bb, 512, 512, 0, 512, As, Bs, acc);

  const int lane = threadIdx.x & 63, wid = threadIdx.x >> 6;
  const int wr = wid >> 1, wc = wid & 1;
#pragma unroll
  for (int n = 0; n < 4; ++n) {
    int col = tn * 128 + wc * 64 + n * 16 + (lane & 15);
#pragma unroll
    for (int m = 0; m < 4; ++m) {
      int r0 = bm * 128 + wr * 64 + m * 16 + (lane >> 4) * 4;
#pragma unroll
      for (int j = 0; j < 4; ++j)
        attn[(long)(r0 + j) * 512 + col] = (bf16)acc[m][n][j];
    }
  }
}

// ---------------- residual add + LayerNorm (one wave per row of 512) ----------------
__global__ __launch_bounds__(256) void ln_kernel(
    const float* __restrict__ x, const bf16* __restrict__ attn,
    const float* __restrict__ gamma, const float* __restrict__ beta,
    float* __restrict__ out)
{
  const int row = blockIdx.x * 4 + (threadIdx.x >> 6);
  const int lane = threadIdx.x & 63;
  const float* xr = x + (long)row * 512;
  const ushort* ar = (const ushort*)attn + (long)row * 512;

  float4 xa = *(const float4*)&xr[lane * 8];
  float4 xb2 = *(const float4*)&xr[lane * 8 + 4];
  uint4 av = *(const uint4*)&ar[lane * 8];
  const ushort* ap = (const ushort*)&av;

  float y[8];
  y[0] = xa.x; y[1] = xa.y; y[2] = xa.z; y[3] = xa.w;
  y[4] = xb2.x; y[5] = xb2.y; y[6] = xb2.z; y[7] = xb2.w;
  float s1 = 0.f, s2 = 0.f;
#pragma unroll
  for (int j = 0; j < 8; ++j) {
    float aj = __uint_as_float(((unsigned)ap[j]) << 16);
    y[j] += aj;
    s1 += y[j];
    s2 += y[j] * y[j];
  }
#pragma unroll
  for (int off = 32; off > 0; off >>= 1) {
    s1 += __shfl_xor(s1, off);
    s2 += __shfl_xor(s2, off);
  }
  float mu = s1 * (1.f / 512.f);
  float var = s2 * (1.f / 512.f) - mu * mu;
  float rs = rsqrtf(var + 1e-5f);

  float4 g0 = *(const float4*)&gamma[lane * 8];
  float4 g1 = *(const float4*)&gamma[lane * 8 + 4];
  float4 b0 = *(const float4*)&beta[lane * 8];
  float4 b1 = *(const float4*)&beta[lane * 8 + 4];
  float4 o0, o1;
  o0.x = (y[0] - mu) * rs * g0.x + b0.x;
  o0.y = (y[1] - mu) * rs * g0.y + b0.y;
  o0.z = (y[2] - mu) * rs * g0.z + b0.z;
  o0.w = (y[3] - mu) * rs * g0.w + b0.w;
  o1.x = (y[4] - mu) * rs * g1.x + b1.x;
  o1.y = (y[5] - mu) * rs * g1.y + b1.y;
  o1.z = (y[6] - mu) * rs * g1.z + b1.z;
  o1.w = (y[7] - mu) * rs * g1.w + b1.w;
  float* orow = out + (long)row * 512 + lane * 8;
  *(float4*)orow = o0;
  *(float4*)(orow + 4) = o1;
}

// ---------------- launch ----------------
extern "C" void kernel_launch(void* const* d_in, const int* in_sizes, int n_in,
                              void* d_out, int out_size, void* d_ws, size_t ws_size,
                              hipStream_t stream) {
  const float* x     = (const float*)d_in[0];
  const float* Wq    = (const float*)d_in[1];
  const float* bq    = (const float*)d_in[2];
  const float* Wk    = (const float*)d_in[3];
  const float* bk    = (const float*)d_in[4];
  const float* Wv    = (const float*)d_in[5];
  const float* bv    = (const float*)d_in[6];
  const float* gamma = (const float*)d_in[7];
  const float* beta  = (const float*)d_in[8];
  float* out = (float*)d_out;

  if (ws_size < (size_t)WS_NEED) return;   // need ~132 MB scratch

  char* ws = (char*)d_ws;
  bf16* xb   = (bf16*)(ws + OFF_XB);
  bf16* Wb   = (bf16*)(ws + OFF_WB);
  bf16* qb   = (bf16*)(ws + OFF_QB);
  bf16* kb   = (bf16*)(ws + OFF_KB);
  bf16* vb   = (bf16*)(ws + OFF_VB);
  bf16* kT   = (bf16*)(ws + OFF_XB);   // reuse xb
  bf16* vT   = (bf16*)(ws + OFF_KB);   // reuse kb
  float* P   = (float*)(ws + OFF_VB);  // reuse vb
  bf16* attn = (bf16*)(ws + OFF_VB);   // reuse vb (after P consumed)
  bf16* KVb  = (bf16*)(ws + OFF_KVB);

  cast_x_kernel<<<2048, 256, 0, stream>>>(x, xb, 2097152);
  cast_w_kernel<<<384, 256, 0, stream>>>(Wq, Wk, Wv, Wb);
  gemm_qkv<<<dim3(256, 12), 256, 0, stream>>>(xb, Wb, bq, bk, bv, qb, kb, vb);
  transpose64<<<dim3(128, 8, 4), 256, 0, stream>>>(kb, kT);
  transpose64<<<dim3(128, 8, 4), 256, 0, stream>>>(vb, vT);
  gemm_kv<<<dim3(16, 8, 4), 256, 0, stream>>>(vT, kT, P);
  reduce_kv<<<1024, 256, 0, stream>>>(P, KVb);
  gemm_attn<<<dim3(256, 4), 256, 0, stream>>>(qb, KVb, attn);
  ln_kernel<<<8192, 256, 0, stream>>>(x, attn, gamma, beta, out);
}

// Round 2
// 199.046 us; speedup vs baseline: 1.1925x; 1.1925x over previous
//
#include <hip/hip_runtime.h>
#include <hip/hip_bf16.h>
#include <stdint.h>

typedef __bf16 bf16;
typedef __attribute__((ext_vector_type(8))) __bf16 bf16x8;
typedef __attribute__((ext_vector_type(4))) __bf16 bf16x4;
typedef __attribute__((ext_vector_type(4))) float f32x4;

// ---------------- workspace layout (bytes) ----------------
// xb  [32768,512] bf16  @0          (dead after gemm_qkv -> P [8,4,512,512] f32 -> attn bf16)
// Wb  [1536,512]  bf16  @33554432
// qb  [32768,512] bf16  @35127296
// kT  [4,512,8192] bf16 @68681728   (written directly by gemm_qkv epilogue)
// vT  [4,512,8192] bf16 @102236160  (written directly by gemm_qkv epilogue)
// KVb [4,512,512] bf16  @135790592
#define OFF_XB   0L
#define OFF_WB   33554432L
#define OFF_QB   35127296L
#define OFF_KT   68681728L
#define OFF_VT   102236160L
#define OFF_KVB  135790592L
#define WS_NEED  137887744L

// ---------------- async global->LDS (16B per lane) ----------------
typedef const __attribute__((address_space(1))) void* gas_p;
typedef __attribute__((address_space(3))) void* las_p;

__device__ __forceinline__ void gload16(const void* g, void* l) {
  __builtin_amdgcn_global_load_lds((gas_p)(uintptr_t)g,
                                   (las_p)(uint32_t)(uintptr_t)l, 16, 0, 0);
}

// ---------------- shared 128x128 B^T-form GEMM core (BK=32) ----------------
// C[128,128] += A[128, kbeg:kend] * B[128, kbeg:kend]^T ; K contiguous in both.
// 256 threads = 4 waves (2x2), each wave 64x64 via 4x4 16x16x32 fragments.
__device__ __forceinline__ void gemm_core(
    const bf16* __restrict__ Ab, const bf16* __restrict__ Bb,
    long lda, long ldb, int kbeg, int kend,
    bf16* As, bf16* Bs, f32x4 (&acc)[4][4])
{
  const int tid  = threadIdx.x;
  const int wid  = tid >> 6;
  const int lane = tid & 63;
  const int wr   = wid >> 1, wc = wid & 1;

  const int rr = wid * 16 + (lane >> 2);
  const int cc = (lane & 3) * 8;
  const bf16* gA0 = Ab + (long)rr * lda + cc;
  const bf16* gA1 = gA0 + 64 * lda;
  const bf16* gB0 = Bb + (long)rr * ldb + cc;
  const bf16* gB1 = gB0 + 64 * ldb;
  bf16* lA0 = As + wid * 512;        // wave-uniform LDS bases
  bf16* lA1 = As + (4 + wid) * 512;
  bf16* lB0 = Bs + wid * 512;
  bf16* lB1 = Bs + (4 + wid) * 512;

  const int aoff = (lane & 15) * 32 + (lane >> 4) * 8;

  for (int k0 = kbeg; k0 < kend; k0 += 32) {
    gload16(gA0 + k0, lA0);
    gload16(gA1 + k0, lA1);
    gload16(gB0 + k0, lB0);
    gload16(gB1 + k0, lB1);
    __syncthreads();   // drains vmcnt -> LDS tiles valid

    bf16x8 af[4], bfr[4];
#pragma unroll
    for (int m = 0; m < 4; ++m)
      af[m] = *(const bf16x8*)(As + (wr * 64 + m * 16) * 32 + aoff);
#pragma unroll
    for (int n = 0; n < 4; ++n)
      bfr[n] = *(const bf16x8*)(Bs + (wc * 64 + n * 16) * 32 + aoff);
#pragma unroll
    for (int m = 0; m < 4; ++m)
#pragma unroll
      for (int n = 0; n < 4; ++n)
        acc[m][n] = __builtin_amdgcn_mfma_f32_16x16x32_bf16(af[m], bfr[n], acc[m][n], 0, 0, 0);
    __syncthreads();   // protect LDS before next stage
  }
}

// ---------------- casts ----------------
__global__ void cast_x_kernel(const float* __restrict__ in, bf16* __restrict__ out, int n8) {
  int i = blockIdx.x * blockDim.x + threadIdx.x;
  int stride = gridDim.x * blockDim.x;
  for (; i < n8; i += stride) {
    const float* p = in + (long)i * 8;
    float4 a = *(const float4*)p;
    float4 b = *(const float4*)(p + 4);
    bf16x8 o;
    o[0] = (bf16)a.x; o[1] = (bf16)a.y; o[2] = (bf16)a.z; o[3] = (bf16)a.w;
    o[4] = (bf16)b.x; o[5] = (bf16)b.y; o[6] = (bf16)b.z; o[7] = (bf16)b.w;
    *(bf16x8*)(out + (long)i * 8) = o;
  }
}

__global__ void cast_w_kernel(const float* __restrict__ Wq, const float* __restrict__ Wk,
                              const float* __restrict__ Wv, bf16* __restrict__ Wb) {
  int i = blockIdx.x * 256 + threadIdx.x;            // 98304 chunks of 8
  const float* src = (i < 32768) ? Wq : (i < 65536) ? Wk : Wv;
  long j = (long)(i & 32767) * 8;
  float4 a = *(const float4*)(src + j);
  float4 b = *(const float4*)(src + j + 4);
  bf16x8 o;
  o[0] = (bf16)a.x; o[1] = (bf16)a.y; o[2] = (bf16)a.z; o[3] = (bf16)a.w;
  o[4] = (bf16)b.x; o[5] = (bf16)b.y; o[6] = (bf16)b.z; o[7] = (bf16)b.w;
  *(bf16x8*)(Wb + (long)i * 8) = o;
}

// ---------------- fused QKV projection GEMM ----------------
// A = xb [32768,512]; B = Wb [1536,512] (q|k|v concat).
// q (+bias,elu1) -> qb [32768,512] row-major.
// k (+bias,elu1) -> kT [4,512,8192] transposed (fused transpose).
// v (+bias)      -> vT [4,512,8192] transposed.
__global__ __launch_bounds__(256) void gemm_qkv(
    const bf16* __restrict__ A, const bf16* __restrict__ Bw,
    const float* __restrict__ bq, const float* __restrict__ bk, const float* __restrict__ bv,
    bf16* __restrict__ qout, bf16* __restrict__ kTout, bf16* __restrict__ vTout)
{
  __shared__ __align__(16) char smem[34816];          // union: 16KB staging | [128][136] bf16 C-tile
  bf16* As = (bf16*)smem;
  bf16* Bs = As + 4096;
  bf16* Ct = (bf16*)smem;                             // epilogue tile, row stride 136

  const int bm = blockIdx.x, tn = blockIdx.y;
  const bf16* Ab = A + (long)bm * 128 * 512;
  const bf16* Bb = Bw + (long)tn * 128 * 512;

  f32x4 acc[4][4] = {};
  gemm_core(Ab, Bb, 512, 512, 0, 512, As, Bs, acc);
  // K-loop ends with __syncthreads(): LDS free to reuse.

  const int tid = threadIdx.x;
  const int lane = tid & 63, wid = tid >> 6;
  const int wr = wid >> 1, wc = wid & 1;
  const int seg = tn >> 2;                            // 0=q 1=k 2=v
  const float* bias = (seg == 0) ? bq : (seg == 1) ? bk : bv;
  const int colbase0 = (tn & 3) * 128;                // tile's global feature-col start

  if (seg == 0) {
    // ---- normal layout: stage bf16 tile, coalesced row writes ----
#pragma unroll
    for (int n = 0; n < 4; ++n) {
      int col = wc * 64 + n * 16 + (lane & 15);
      float bia = bias[colbase0 + col];
#pragma unroll
      for (int m = 0; m < 4; ++m) {
        int r0 = wr * 64 + m * 16 + (lane >> 4) * 4;
#pragma unroll
        for (int j = 0; j < 4; ++j) {
          float v = acc[m][n][j] + bia;
          v = (v > 0.f) ? (v + 1.f) : __expf(v);
          Ct[(r0 + j) * 136 + col] = (bf16)v;
        }
      }
    }
    __syncthreads();
    const long rowbase = (long)bm * 128;
    const int r_ = tid >> 4, c8 = (tid & 15) * 8;
#pragma unroll
    for (int p = 0; p < 8; ++p) {
      int row = p * 16 + r_;
      bf16x8 v = *(const bf16x8*)(Ct + row * 136 + c8);
      *(bf16x8*)(qout + (rowbase + row) * 512 + colbase0 + c8) = v;
    }
  } else {
    // ---- transposed: stage C^T (Ct[d_local][s_local]), write [b][d][s] coalesced ----
    bf16* outT = (seg == 1) ? kTout : vTout;
#pragma unroll
    for (int n = 0; n < 4; ++n) {
      int col = wc * 64 + n * 16 + (lane & 15);       // d_local
      float bia = bias[colbase0 + col];
#pragma unroll
      for (int m = 0; m < 4; ++m) {
        int r0 = wr * 64 + m * 16 + (lane >> 4) * 4;  // s_local
        bf16x4 pack;
#pragma unroll
        for (int j = 0; j < 4; ++j) {
          float v = acc[m][n][j] + bia;
          if (seg == 1) v = (v > 0.f) ? (v + 1.f) : __expf(v);
          pack[j] = (bf16)v;
        }
        *(bf16x4*)(Ct + col * 136 + r0) = pack;
      }
    }
    __syncthreads();
    const int b = bm >> 6;
    const long sb = (long)(bm & 63) * 128;
    const int d_ = tid >> 4, s8 = (tid & 15) * 8;
    bf16* outB = outT + (long)b * 512 * 8192 + sb;
#pragma unroll
    for (int p = 0; p < 8; ++p) {
      int d = p * 16 + d_;
      bf16x8 v = *(const bf16x8*)(Ct + d * 136 + s8);
      *(bf16x8*)(outB + (long)(colbase0 + d) * 8192 + s8) = v;
    }
  }
}

// ---------------- KV^T GEMM, split-K=8 (deterministic partials) ----------------
// C[e,d] = sum_s v[s,e]*k[s,d] ; A = vT rows e, B = kT rows d, K = s.
__global__ __launch_bounds__(256) void gemm_kv(
    const bf16* __restrict__ vT, const bf16* __restrict__ kT, float* __restrict__ P)
{
  __shared__ __align__(16) bf16 As[4096];
  __shared__ __align__(16) bf16 Bs[4096];
  const int te = blockIdx.x >> 2, td = blockIdx.x & 3;
  const int sk = blockIdx.y, b = blockIdx.z;
  const bf16* Ab = vT + (long)b * 512 * 8192 + (long)te * 128 * 8192;
  const bf16* Bb = kT + (long)b * 512 * 8192 + (long)td * 128 * 8192;

  f32x4 acc[4][4] = {};
  gemm_core(Ab, Bb, 8192, 8192, sk * 1024, sk * 1024 + 1024, As, Bs, acc);

  const int lane = threadIdx.x & 63, wid = threadIdx.x >> 6;
  const int wr = wid >> 1, wc = wid & 1;
  float* Cb = P + ((long)sk * 4 + b) * 262144;
#pragma unroll
  for (int n = 0; n < 4; ++n) {
    int d = td * 128 + wc * 64 + n * 16 + (lane & 15);
#pragma unroll
    for (int m = 0; m < 4; ++m) {
      int e0 = te * 128 + wr * 64 + m * 16 + (lane >> 4) * 4;
#pragma unroll
      for (int j = 0; j < 4; ++j)
        Cb[(long)(e0 + j) * 512 + d] = acc[m][n][j];   // 64B-contiguous segments
    }
  }
}

__global__ void reduce_kv(const float* __restrict__ P, bf16* __restrict__ KVb) {
  long o = ((long)blockIdx.x * 256 + threadIdx.x) * 4;   // over 4*512*512 elems
  int b = (int)(o >> 18);
  long rem = o & 262143L;
  float4 s = make_float4(0.f, 0.f, 0.f, 0.f);
  for (int sk = 0; sk < 8; ++sk) {
    float4 p = *(const float4*)(P + ((long)sk * 4 + b) * 262144 + rem);
    s.x += p.x; s.y += p.y; s.z += p.z; s.w += p.w;
  }
  bf16x4 ov;
  ov[0] = (bf16)s.x; ov[1] = (bf16)s.y; ov[2] = (bf16)s.z; ov[3] = (bf16)s.w;
  *(bf16x4*)(KVb + o) = ov;
}

// ---------------- attn GEMM: C[s,e] = sum_d q[s,d]*KVT[e,d] ----------------
__global__ __launch_bounds__(256) void gemm_attn(
    const bf16* __restrict__ Q, const bf16* __restrict__ KVb, bf16* __restrict__ attn)
{
  __shared__ __align__(16) char smem[34816];
  bf16* As = (bf16*)smem;
  bf16* Bs = As + 4096;
  bf16* Ct = (bf16*)smem;

  const int bm = blockIdx.x, tn = blockIdx.y;
  const int b = bm >> 6;                       // 64 m-tiles per batch
  const bf16* Ab = Q + (long)bm * 128 * 512;
  const bf16* Bb = KVb + (long)b * 262144 + (long)tn * 128 * 512;

  f32x4 acc[4][4] = {};
  gemm_core(Ab, Bb, 512, 512, 0, 512, As, Bs, acc);

  const int tid = threadIdx.x;
  const int lane = tid & 63, wid = tid >> 6;
  const int wr = wid >> 1, wc = wid & 1;
#pragma unroll
  for (int n = 0; n < 4; ++n) {
    int col = wc * 64 + n * 16 + (lane & 15);
#pragma unroll
    for (int m = 0; m < 4; ++m) {
      int r0 = wr * 64 + m * 16 + (lane >> 4) * 4;
#pragma unroll
      for (int j = 0; j < 4; ++j)
        Ct[(r0 + j) * 136 + col] = (bf16)acc[m][n][j];
    }
  }
  __syncthreads();
  const long rowbase = (long)bm * 128;
  const int colbase0 = tn * 128;
  const int r_ = tid >> 4, c8 = (tid & 15) * 8;
#pragma unroll
  for (int p = 0; p < 8; ++p) {
    int row = p * 16 + r_;
    bf16x8 v = *(const bf16x8*)(Ct + row * 136 + c8);
    *(bf16x8*)(attn + (rowbase + row) * 512 + colbase0 + c8) = v;
  }
}

// ---------------- residual add + LayerNorm (one wave per row of 512) ----------------
__global__ __launch_bounds__(256) void ln_kernel(
    const float* __restrict__ x, const bf16* __restrict__ attn,
    const float* __restrict__ gamma, const float* __restrict__ beta,
    float* __restrict__ out)
{
  const int row = blockIdx.x * 4 + (threadIdx.x >> 6);
  const int lane = threadIdx.x & 63;
  const float* xr = x + (long)row * 512;
  const ushort* ar = (const ushort*)attn + (long)row * 512;

  float4 xa = *(const float4*)&xr[lane * 8];
  float4 xb2 = *(const float4*)&xr[lane * 8 + 4];
  uint4 av = *(const uint4*)&ar[lane * 8];
  const ushort* ap = (const ushort*)&av;

  float y[8];
  y[0] = xa.x; y[1] = xa.y; y[2] = xa.z; y[3] = xa.w;
  y[4] = xb2.x; y[5] = xb2.y; y[6] = xb2.z; y[7] = xb2.w;
  float s1 = 0.f, s2 = 0.f;
#pragma unroll
  for (int j = 0; j < 8; ++j) {
    float aj = __uint_as_float(((unsigned)ap[j]) << 16);
    y[j] += aj;
    s1 += y[j];
    s2 += y[j] * y[j];
  }
#pragma unroll
  for (int off = 32; off > 0; off >>= 1) {
    s1 += __shfl_xor(s1, off);
    s2 += __shfl_xor(s2, off);
  }
  float mu = s1 * (1.f / 512.f);
  float var = s2 * (1.f / 512.f) - mu * mu;
  float rs = rsqrtf(var + 1e-5f);

  float4 g0 = *(const float4*)&gamma[lane * 8];
  float4 g1 = *(const float4*)&gamma[lane * 8 + 4];
  float4 b0 = *(const float4*)&beta[lane * 8];
  float4 b1 = *(const float4*)&beta[lane * 8 + 4];
  float4 o0, o1;
  o0.x = (y[0] - mu) * rs * g0.x + b0.x;
  o0.y = (y[1] - mu) * rs * g0.y + b0.y;
  o0.z = (y[2] - mu) * rs * g0.z + b0.z;
  o0.w = (y[3] - mu) * rs * g0.w + b0.w;
  o1.x = (y[4] - mu) * rs * g1.x + b1.x;
  o1.y = (y[5] - mu) * rs * g1.y + b1.y;
  o1.z = (y[6] - mu) * rs * g1.z + b1.z;
  o1.w = (y[7] - mu) * rs * g1.w + b1.w;
  float* orow = out + (long)row * 512 + lane * 8;
  *(float4*)orow = o0;
  *(float4*)(orow + 4) = o1;
}

// ---------------- launch ----------------
extern "C" void kernel_launch(void* const* d_in, const int* in_sizes, int n_in,
                              void* d_out, int out_size, void* d_ws, size_t ws_size,
                              hipStream_t stream) {
  const float* x     = (const float*)d_in[0];
  const float* Wq    = (const float*)d_in[1];
  const float* bq    = (const float*)d_in[2];
  const float* Wk    = (const float*)d_in[3];
  const float* bk    = (const float*)d_in[4];
  const float* Wv    = (const float*)d_in[5];
  const float* bv    = (const float*)d_in[6];
  const float* gamma = (const float*)d_in[7];
  const float* beta  = (const float*)d_in[8];
  float* out = (float*)d_out;

  if (ws_size < (size_t)WS_NEED) return;   // need ~132 MB scratch

  char* ws = (char*)d_ws;
  bf16* xb   = (bf16*)(ws + OFF_XB);
  bf16* Wb   = (bf16*)(ws + OFF_WB);
  bf16* qb   = (bf16*)(ws + OFF_QB);
  bf16* kT   = (bf16*)(ws + OFF_KT);
  bf16* vT   = (bf16*)(ws + OFF_VT);
  float* P   = (float*)(ws + OFF_XB);  // reuse xb (dead after gemm_qkv), 33.55 MB exact
  bf16* attn = (bf16*)(ws + OFF_XB);   // reuse again after P consumed
  bf16* KVb  = (bf16*)(ws + OFF_KVB);

  cast_x_kernel<<<2048, 256, 0, stream>>>(x, xb, 2097152);
  cast_w_kernel<<<384, 256, 0, stream>>>(Wq, Wk, Wv, Wb);
  gemm_qkv<<<dim3(256, 12), 256, 0, stream>>>(xb, Wb, bq, bk, bv, qb, kT, vT);
  gemm_kv<<<dim3(16, 8, 4), 256, 0, stream>>>(vT, kT, P);
  reduce_kv<<<1024, 256, 0, stream>>>(P, KVb);
  gemm_attn<<<dim3(256, 4), 256, 0, stream>>>(qb, KVb, attn);
  ln_kernel<<<8192, 256, 0, stream>>>(x, attn, gamma, beta, out);
}